// Round 1
// baseline (529.691 us; speedup 1.0000x reference)
//
#include <hip/hip_runtime.h>
#include <hip/hip_bf16.h>

// ---------------------------------------------------------------------------
// Problem constants: B=4, T=2048, C=1024, H=16, hd=64
// ---------------------------------------------------------------------------
#define BATCH 4
#define TSEQ  2048
#define CDIM  1024
#define NHEAD 16
#define HDIM  64
#define C3    3072
#define MROWS (BATCH * TSEQ)   // 8192

typedef short bf16x8 __attribute__((ext_vector_type(8)));
typedef __bf16 bf16v8 __attribute__((ext_vector_type(8)));
typedef float f32x4 __attribute__((ext_vector_type(4)));

#define AS1 __attribute__((address_space(1)))
#define AS3 __attribute__((address_space(3)))

__device__ __forceinline__ short f2bf(float x) {
    unsigned int u = __builtin_bit_cast(unsigned int, x);
    u += 0x7fffu + ((u >> 16) & 1u);   // round-to-nearest-even
    return (short)(u >> 16);
}

__device__ __forceinline__ f32x4 mfma16(bf16x8 a, bf16x8 b, f32x4 c) {
    return __builtin_amdgcn_mfma_f32_16x16x32_bf16(
        __builtin_bit_cast(bf16v8, a), __builtin_bit_cast(bf16v8, b), c, 0, 0, 0);
}

// ---------------------------------------------------------------------------
// fp32 -> bf16 straight convert (vectorized, n multiple of 4)
// ---------------------------------------------------------------------------
__global__ void f32_to_bf16_kernel(const float* __restrict__ in,
                                   short* __restrict__ out, int n4) {
    int i = blockIdx.x * blockDim.x + threadIdx.x;
    if (i >= n4) return;
    float4 v = ((const float4*)in)[i];
    short4 o;
    o.x = f2bf(v.x); o.y = f2bf(v.y); o.z = f2bf(v.z); o.w = f2bf(v.w);
    ((short4*)out)[i] = o;
}

// ---------------------------------------------------------------------------
// fp32 [K][N] -> bf16 [N][K] transpose-convert (32x32 LDS tiles)
// ---------------------------------------------------------------------------
__global__ void transpose_f32_bf16_kernel(const float* __restrict__ in,
                                          short* __restrict__ out,
                                          int K, int N) {
    __shared__ float tile[32][33];
    const int n0 = blockIdx.x * 32, k0 = blockIdx.y * 32;
    const int tx = threadIdx.x, ty = threadIdx.y;   // (32,8)
#pragma unroll
    for (int j = 0; j < 4; ++j)
        tile[ty + j * 8][tx] = in[(size_t)(k0 + ty + j * 8) * N + n0 + tx];
    __syncthreads();
#pragma unroll
    for (int j = 0; j < 4; ++j)
        out[(size_t)(n0 + ty + j * 8) * K + k0 + tx] = f2bf(tile[tx][ty + j * 8]);
}

// ---------------------------------------------------------------------------
// bf16 GEMM, m97 structure: out[M][N] = A[M][K] * Bt[N][K]^T + bias[N]
// 128x128 tile, BK=32, 4 waves (2x2), global_load_lds width-16 staging.
// ---------------------------------------------------------------------------
template <typename OutT>
__global__ __launch_bounds__(256) void gemm_bt_kernel(
    const short* __restrict__ A, const short* __restrict__ Bt,
    const float* __restrict__ bias, OutT* __restrict__ out,
    int M, int N, int K) {
    __shared__ short a_lds[128 * 32];
    __shared__ short b_lds[128 * 32];

    const int tid = threadIdx.x;
    const int lane = tid & 63;
    const int w = tid >> 6;
    const int wm = w >> 1, wn = w & 1;
    const int m0 = blockIdx.y * 128;
    const int n0 = blockIdx.x * 128;

    f32x4 acc[4][4] = {};

    // staging geometry: wave w, call c covers rows w*32 + c*16 + (lane>>2),
    // k-cols (lane&3)*8 .. +7 ; LDS dest = (w*2+c)*512 + lane*8 (linear match)
    const int srow = lane >> 2;
    const int scol = (lane & 3) * 8;
    const short* ga0 = A + (size_t)(m0 + w * 32 + srow) * K + scol;
    const short* ga1 = A + (size_t)(m0 + w * 32 + 16 + srow) * K + scol;
    const short* gb0 = Bt + (size_t)(n0 + w * 32 + srow) * K + scol;
    const short* gb1 = Bt + (size_t)(n0 + w * 32 + 16 + srow) * K + scol;
    short* la0 = &a_lds[(w * 2 + 0) * 512];
    short* la1 = &a_lds[(w * 2 + 1) * 512];
    short* lb0 = &b_lds[(w * 2 + 0) * 512];
    short* lb1 = &b_lds[(w * 2 + 1) * 512];

    const int fr = lane & 15;        // fragment row/col within 16
    const int kg = (lane >> 4) * 8;  // k-group offset

    for (int kt = 0; kt < K; kt += 32) {
        __syncthreads();
        __builtin_amdgcn_global_load_lds((const AS1 void*)(ga0 + kt), (AS3 void*)la0, 16, 0, 0);
        __builtin_amdgcn_global_load_lds((const AS1 void*)(ga1 + kt), (AS3 void*)la1, 16, 0, 0);
        __builtin_amdgcn_global_load_lds((const AS1 void*)(gb0 + kt), (AS3 void*)lb0, 16, 0, 0);
        __builtin_amdgcn_global_load_lds((const AS1 void*)(gb1 + kt), (AS3 void*)lb1, 16, 0, 0);
        __syncthreads();

        bf16x8 af[4], bfv[4];
#pragma unroll
        for (int f = 0; f < 4; ++f)
            af[f] = *(const bf16x8*)&a_lds[(wm * 64 + f * 16 + fr) * 32 + kg];
#pragma unroll
        for (int g = 0; g < 4; ++g)
            bfv[g] = *(const bf16x8*)&b_lds[(wn * 64 + g * 16 + fr) * 32 + kg];
#pragma unroll
        for (int f = 0; f < 4; ++f)
#pragma unroll
            for (int g = 0; g < 4; ++g)
                acc[f][g] = mfma16(af[f], bfv[g], acc[f][g]);
    }

    // epilogue: D row = (lane>>4)*4 + r (M dim), col = lane&15 (N dim)
    const int r0 = (lane >> 4) * 4;
    const int cn = lane & 15;
#pragma unroll
    for (int f = 0; f < 4; ++f) {
#pragma unroll
        for (int g = 0; g < 4; ++g) {
            const int col = n0 + wn * 64 + g * 16 + cn;
            const float bv = bias[col];
#pragma unroll
            for (int r = 0; r < 4; ++r) {
                const int row = m0 + wm * 64 + f * 16 + r0 + r;
                const float v = acc[f][g][r] + bv;
                if constexpr (sizeof(OutT) == 2)
                    out[(size_t)row * N + col] = (OutT)f2bf(v);
                else
                    out[(size_t)row * N + col] = (OutT)v;
            }
        }
    }
}

// ---------------------------------------------------------------------------
// Flash attention: grid (T/64, B*H), 256 threads = 4 waves, wave owns 16 q rows.
// qkv layout: [B*T][3C] bf16 rows: [q(1024) | k(1024) | v(1024)], head h at h*64.
// ---------------------------------------------------------------------------
__global__ __launch_bounds__(256) void attn_kernel(const short* __restrict__ qkv,
                                                   short* __restrict__ attn_out) {
    __shared__ short vt_lds[HDIM * 40];      // V^T tile: [d][kv], stride 40
    __shared__ short p_lds[4 * 16 * 40];     // per-wave P: [q16][kv32], stride 40

    const int tid = threadIdx.x;
    const int lane = tid & 63;
    const int w = tid >> 6;
    const int b = blockIdx.y >> 4;
    const int h = blockIdx.y & 15;
    const int q0 = blockIdx.x * 64;
    const int qrow = q0 + w * 16;

    const size_t base = (size_t)b * TSEQ * C3 + (size_t)h * HDIM;
    const int fr = lane & 15;
    const int kg8 = (lane >> 4) * 8;
    const int r0 = (lane >> 4) * 4;
    const int cn = lane & 15;

    // Q fragments (hoisted): A-operand, row = q local = lane&15, k = hd
    bf16x8 qf[2];
    {
        const short* qp = qkv + base + (size_t)(qrow + fr) * C3 + kg8;
        qf[0] = *(const bf16x8*)qp;
        qf[1] = *(const bf16x8*)(qp + 32);
    }

    f32x4 ao[4] = {};          // O accumulator: 4 d-tiles of 16
    float mrow[4], lrow[4];
#pragma unroll
    for (int r = 0; r < 4; ++r) { mrow[r] = -__builtin_inff(); lrow[r] = 0.f; }

    const int nkv = (q0 + 64) / 32;

    for (int kb = 0; kb < nkv; ++kb) {
        const int kvb = kb * 32;
        __syncthreads();   // prior PV reads of vt_lds done
        // stage V^T: thread t handles kv = t>>3, d = (t&7)*8 .. +7
        {
            const int kvloc = tid >> 3;
            const int d0 = (tid & 7) * 8;
            const short* vp = qkv + base + 2048 + (size_t)(kvb + kvloc) * C3 + d0;
            bf16x8 v = *(const bf16x8*)vp;
#pragma unroll
            for (int i = 0; i < 8; ++i) vt_lds[(d0 + i) * 40 + kvloc] = v[i];
        }
        __syncthreads();

        // QK^T: S[16q][32kv], two 16-col tiles
        f32x4 s[2] = {};
#pragma unroll
        for (int nt = 0; nt < 2; ++nt) {
            const short* kp = qkv + base + 1024 + (size_t)(kvb + nt * 16 + fr) * C3 + kg8;
            bf16x8 k0 = *(const bf16x8*)kp;
            bf16x8 k1 = *(const bf16x8*)(kp + 32);
            s[nt] = mfma16(qf[0], k0, s[nt]);
            s[nt] = mfma16(qf[1], k1, s[nt]);
        }

        // online softmax (rows live in 16-lane groups)
        float p0[4], p1[4], scl[4];
#pragma unroll
        for (int r = 0; r < 4; ++r) {
            const int q = qrow + r0 + r;
            float s0 = s[0][r] * 0.125f;
            float s1 = s[1][r] * 0.125f;
            if (kvb + cn > q)      s0 = -__builtin_inff();
            if (kvb + 16 + cn > q) s1 = -__builtin_inff();
            float t = fmaxf(s0, s1);
            t = fmaxf(t, __shfl_xor(t, 1));
            t = fmaxf(t, __shfl_xor(t, 2));
            t = fmaxf(t, __shfl_xor(t, 4));
            t = fmaxf(t, __shfl_xor(t, 8));
            const float mn = fmaxf(mrow[r], t);
            const float sc = __expf(mrow[r] - mn);
            const float e0 = __expf(s0 - mn);
            const float e1 = __expf(s1 - mn);
            float rs = e0 + e1;
            rs += __shfl_xor(rs, 1);
            rs += __shfl_xor(rs, 2);
            rs += __shfl_xor(rs, 4);
            rs += __shfl_xor(rs, 8);
            lrow[r] = lrow[r] * sc + rs;
            mrow[r] = mn;
            scl[r] = sc;
            p0[r] = e0; p1[r] = e1;
        }
#pragma unroll
        for (int dt = 0; dt < 4; ++dt)
#pragma unroll
            for (int r = 0; r < 4; ++r) ao[dt][r] *= scl[r];

        // P -> LDS (D layout) then re-read as A fragments
        short* pw = &p_lds[w * 640];
#pragma unroll
        for (int r = 0; r < 4; ++r) {
            pw[(r0 + r) * 40 + cn]      = f2bf(p0[r]);
            pw[(r0 + r) * 40 + 16 + cn] = f2bf(p1[r]);
        }
        __syncthreads();

        // PV: O[16q][64d] += P[16q][32kv] * V[32kv][64d]
        bf16x8 pf = *(const bf16x8*)&p_lds[w * 640 + fr * 40 + kg8];
#pragma unroll
        for (int dt = 0; dt < 4; ++dt) {
            bf16x8 vf = *(const bf16x8*)&vt_lds[(dt * 16 + fr) * 40 + kg8];
            ao[dt] = mfma16(pf, vf, ao[dt]);
        }
    }

    // epilogue: attn_out[B*T][C], col = h*64 + dt*16 + cn
#pragma unroll
    for (int dt = 0; dt < 4; ++dt) {
#pragma unroll
        for (int r = 0; r < 4; ++r) {
            const int q = qrow + r0 + r;
            const float v = ao[dt][r] / lrow[r];
            attn_out[(size_t)(b * TSEQ + q) * CDIM + h * HDIM + dt * 16 + cn] = f2bf(v);
        }
    }
}

// ---------------------------------------------------------------------------
// launch
// ---------------------------------------------------------------------------
extern "C" void kernel_launch(void* const* d_in, const int* in_sizes, int n_in,
                              void* d_out, int out_size, void* d_ws, size_t ws_size,
                              hipStream_t stream) {
    const float* x      = (const float*)d_in[0];
    const float* w_attn = (const float*)d_in[1];
    const float* b_attn = (const float*)d_in[2];
    const float* w_proj = (const float*)d_in[3];
    const float* b_proj = (const float*)d_in[4];
    float* out = (float*)d_out;

    char* ws = (char*)d_ws;
    short* x_bf   = (short*)ws;                          // 16 MiB [8192][1024]; reused as attn out
    short* wqkvT  = (short*)(ws + (16u << 20));          //  6 MiB [3072][1024]
    short* wprojT = (short*)(ws + (22u << 20));          //  2 MiB [1024][1024]
    short* qkv    = (short*)(ws + (24u << 20));          // 48 MiB [8192][3072]

    // 1) conversions
    f32_to_bf16_kernel<<<(MROWS * CDIM / 4 + 255) / 256, 256, 0, stream>>>(x, x_bf, MROWS * CDIM / 4);
    transpose_f32_bf16_kernel<<<dim3(C3 / 32, CDIM / 32), dim3(32, 8), 0, stream>>>(w_attn, wqkvT, CDIM, C3);
    transpose_f32_bf16_kernel<<<dim3(CDIM / 32, CDIM / 32), dim3(32, 8), 0, stream>>>(w_proj, wprojT, CDIM, CDIM);

    // 2) qkv = x @ w_attn + b_attn   (bf16 out)
    gemm_bt_kernel<short><<<dim3(C3 / 128, MROWS / 128), 256, 0, stream>>>(
        x_bf, wqkvT, b_attn, qkv, MROWS, C3, CDIM);

    // 3) flash attention (writes attn into x_bf region — x_bf is dead now)
    attn_kernel<<<dim3(TSEQ / 64, BATCH * NHEAD), 256, 0, stream>>>(qkv, x_bf);

    // 4) out = attn @ w_proj + b_proj  (fp32 out)
    gemm_bt_kernel<float><<<dim3(CDIM / 128, MROWS / 128), 256, 0, stream>>>(
        x_bf, wprojT, b_proj, out, MROWS, CDIM, CDIM);
}

// Round 2
// 366.813 us; speedup vs baseline: 1.4440x; 1.4440x over previous
//
#include <hip/hip_runtime.h>
#include <hip/hip_bf16.h>

// ---------------------------------------------------------------------------
// Problem constants: B=4, T=2048, C=1024, H=16, hd=64
// ---------------------------------------------------------------------------
#define BATCH 4
#define TSEQ  2048
#define CDIM  1024
#define NHEAD 16
#define HDIM  64
#define C3    3072
#define MROWS (BATCH * TSEQ)   // 8192

typedef short bf16x8 __attribute__((ext_vector_type(8)));
typedef __bf16 bf16v8 __attribute__((ext_vector_type(8)));
typedef float f32x4 __attribute__((ext_vector_type(4)));

#define AS1 __attribute__((address_space(1)))
#define AS3 __attribute__((address_space(3)))

__device__ __forceinline__ short f2bf(float x) {
    unsigned int u = __builtin_bit_cast(unsigned int, x);
    u += 0x7fffu + ((u >> 16) & 1u);   // round-to-nearest-even
    return (short)(u >> 16);
}

__device__ __forceinline__ f32x4 mfma16(bf16x8 a, bf16x8 b, f32x4 c) {
    return __builtin_amdgcn_mfma_f32_16x16x32_bf16(
        __builtin_bit_cast(bf16v8, a), __builtin_bit_cast(bf16v8, b), c, 0, 0, 0);
}

// ---------------------------------------------------------------------------
// fp32 -> bf16 straight convert (vectorized, n multiple of 4)
// ---------------------------------------------------------------------------
__global__ void f32_to_bf16_kernel(const float* __restrict__ in,
                                   short* __restrict__ out, int n4) {
    int i = blockIdx.x * blockDim.x + threadIdx.x;
    if (i >= n4) return;
    float4 v = ((const float4*)in)[i];
    short4 o;
    o.x = f2bf(v.x); o.y = f2bf(v.y); o.z = f2bf(v.z); o.w = f2bf(v.w);
    ((short4*)out)[i] = o;
}

// ---------------------------------------------------------------------------
// fp32 [K][N] -> bf16 [N][K] transpose-convert (32x32 LDS tiles)
// ---------------------------------------------------------------------------
__global__ void transpose_f32_bf16_kernel(const float* __restrict__ in,
                                          short* __restrict__ out,
                                          int K, int N) {
    __shared__ float tile[32][33];
    const int n0 = blockIdx.x * 32, k0 = blockIdx.y * 32;
    const int tx = threadIdx.x, ty = threadIdx.y;   // (32,8)
#pragma unroll
    for (int j = 0; j < 4; ++j)
        tile[ty + j * 8][tx] = in[(size_t)(k0 + ty + j * 8) * N + n0 + tx];
    __syncthreads();
#pragma unroll
    for (int j = 0; j < 4; ++j)
        out[(size_t)(n0 + ty + j * 8) * K + k0 + tx] = f2bf(tile[tx][ty + j * 8]);
}

// ---------------------------------------------------------------------------
// bf16 GEMM, m97 structure: out[M][N] = A[M][K] * Bt[N][K]^T + bias[N]
// ---------------------------------------------------------------------------
template <typename OutT>
__global__ __launch_bounds__(256) void gemm_bt_kernel(
    const short* __restrict__ A, const short* __restrict__ Bt,
    const float* __restrict__ bias, OutT* __restrict__ out,
    int M, int N, int K) {
    __shared__ short a_lds[128 * 32];
    __shared__ short b_lds[128 * 32];

    const int tid = threadIdx.x;
    const int lane = tid & 63;
    const int w = tid >> 6;
    const int wm = w >> 1, wn = w & 1;
    const int m0 = blockIdx.y * 128;
    const int n0 = blockIdx.x * 128;

    f32x4 acc[4][4] = {};

    const int srow = lane >> 2;
    const int scol = (lane & 3) * 8;
    const short* ga0 = A + (size_t)(m0 + w * 32 + srow) * K + scol;
    const short* ga1 = A + (size_t)(m0 + w * 32 + 16 + srow) * K + scol;
    const short* gb0 = Bt + (size_t)(n0 + w * 32 + srow) * K + scol;
    const short* gb1 = Bt + (size_t)(n0 + w * 32 + 16 + srow) * K + scol;
    short* la0 = &a_lds[(w * 2 + 0) * 512];
    short* la1 = &a_lds[(w * 2 + 1) * 512];
    short* lb0 = &b_lds[(w * 2 + 0) * 512];
    short* lb1 = &b_lds[(w * 2 + 1) * 512];

    const int fr = lane & 15;
    const int kg = (lane >> 4) * 8;

    for (int kt = 0; kt < K; kt += 32) {
        __syncthreads();
        __builtin_amdgcn_global_load_lds((const AS1 void*)(ga0 + kt), (AS3 void*)la0, 16, 0, 0);
        __builtin_amdgcn_global_load_lds((const AS1 void*)(ga1 + kt), (AS3 void*)la1, 16, 0, 0);
        __builtin_amdgcn_global_load_lds((const AS1 void*)(gb0 + kt), (AS3 void*)lb0, 16, 0, 0);
        __builtin_amdgcn_global_load_lds((const AS1 void*)(gb1 + kt), (AS3 void*)lb1, 16, 0, 0);
        __syncthreads();

        bf16x8 af[4], bfv[4];
#pragma unroll
        for (int f = 0; f < 4; ++f)
            af[f] = *(const bf16x8*)&a_lds[(wm * 64 + f * 16 + fr) * 32 + kg];
#pragma unroll
        for (int g = 0; g < 4; ++g)
            bfv[g] = *(const bf16x8*)&b_lds[(wn * 64 + g * 16 + fr) * 32 + kg];
#pragma unroll
        for (int f = 0; f < 4; ++f)
#pragma unroll
            for (int g = 0; g < 4; ++g)
                acc[f][g] = mfma16(af[f], bfv[g], acc[f][g]);
    }

    const int r0 = (lane >> 4) * 4;
    const int cn = lane & 15;
#pragma unroll
    for (int f = 0; f < 4; ++f) {
#pragma unroll
        for (int g = 0; g < 4; ++g) {
            const int col = n0 + wn * 64 + g * 16 + cn;
            const float bv = bias[col];
#pragma unroll
            for (int r = 0; r < 4; ++r) {
                const int row = m0 + wm * 64 + f * 16 + r0 + r;
                const float v = acc[f][g][r] + bv;
                if constexpr (sizeof(OutT) == 2)
                    out[(size_t)row * N + col] = (OutT)f2bf(v);
                else
                    out[(size_t)row * N + col] = (OutT)v;
            }
        }
    }
}

// ---------------------------------------------------------------------------
// Flash attention v2 — swapped QK^T orientation.
// grid (T/128, B*H), 256 threads = 4 waves; wave owns 32 q rows; KVBLK=64.
// S^T = mfma(A=K, B=Q): D col = q-local (lane&15), row = kv-local (4g+r).
// Softmax in-register (2 shfl_xor per reduction); P redistributed to the PV
// A-fragment layout via __shfl pulls; V^T double-buffered in LDS (stride 72).
// ---------------------------------------------------------------------------
__global__ __launch_bounds__(256) void attn_kernel(const short* __restrict__ qkv,
                                                   short* __restrict__ attn_out) {
    __shared__ short vt[2][64 * 72];   // [buf][d*72 + kv], 144B row stride

    const int tid = threadIdx.x;
    const int lane = tid & 63;
    const int w = tid >> 6;
    const int b = blockIdx.y >> 4;
    const int h = blockIdx.y & 15;
    const int q0 = blockIdx.x * 128;
    const int qrow = q0 + w * 32;

    const size_t base = (size_t)b * TSEQ * C3 + (size_t)h * HDIM;
    const int cn = lane & 15;
    const int g = lane >> 4;
    const int kg8 = g * 8;

    // Q fragments (B-operand): col=cn=q-local, k-elems = d = ks*32 + kg8 + j
    bf16x8 qf[2][2];
#pragma unroll
    for (int qt = 0; qt < 2; ++qt)
#pragma unroll
        for (int ks = 0; ks < 2; ++ks)
            qf[qt][ks] = *(const bf16x8*)(qkv + base +
                (size_t)(qrow + qt * 16 + cn) * C3 + ks * 32 + kg8);

    f32x4 ao[2][4] = {};               // O: [qt][dt], row=q-local 4g+r, col=d-local cn
    float mrow[2] = {-3.0e38f, -3.0e38f};
    float lrow[2] = {0.f, 0.f};

    const int niter = (q0 + 128) / 64;

    // V staging: thread covers kv rows (skv, skv+1) x d cols sd0..sd0+7
    const int skv = (tid & 31) * 2;
    const int sd0 = (tid >> 5) * 8;
    const short* vbase = qkv + base + 2048;

    {   // prologue: stage kv-block 0 into vt[0]
        bf16x8 r0 = *(const bf16x8*)(vbase + (size_t)skv * C3 + sd0);
        bf16x8 r1 = *(const bf16x8*)(vbase + (size_t)(skv + 1) * C3 + sd0);
#pragma unroll
        for (int i = 0; i < 8; ++i) {
            unsigned int pk = (unsigned short)r0[i] | ((unsigned int)(unsigned short)r1[i] << 16);
            *(unsigned int*)&vt[0][(sd0 + i) * 72 + skv] = pk;
        }
    }
    __syncthreads();

    for (int kb = 0; kb < niter; ++kb) {
        const int kvb = kb * 64;
        const int cur = kb & 1;

        // T14 async-stage: issue next V-tile global loads before compute
        bf16x8 r0, r1;
        const bool pf = (kb + 1 < niter);
        if (pf) {
            r0 = *(const bf16x8*)(vbase + (size_t)(kvb + 64 + skv) * C3 + sd0);
            r1 = *(const bf16x8*)(vbase + (size_t)(kvb + 64 + skv + 1) * C3 + sd0);
        }

        if (kvb <= qrow + 31) {        // wave-uniform activity guard
            // K fragments (A-operand): row=cn=kv-local, k = d
            bf16x8 kf[4][2];
#pragma unroll
            for (int t = 0; t < 4; ++t)
#pragma unroll
                for (int ks = 0; ks < 2; ++ks)
                    kf[t][ks] = *(const bf16x8*)(qkv + base + 1024 +
                        (size_t)(kvb + t * 16 + cn) * C3 + ks * 32 + kg8);

            // S^T[kv][q] per (qt, kv-tile)
            f32x4 s[2][4] = {};
#pragma unroll
            for (int qt = 0; qt < 2; ++qt)
#pragma unroll
                for (int t = 0; t < 4; ++t) {
                    s[qt][t] = mfma16(kf[t][0], qf[qt][0], s[qt][t]);
                    s[qt][t] = mfma16(kf[t][1], qf[qt][1], s[qt][t]);
                }

            const bool maskIter = (kvb + 63 > qrow);
            const float sc2 = 0.125f * 1.44269504088896f;   // scale * log2(e)

            unsigned int wq[2][8];     // packed bf16 P pairs: [qt][t*2 + half]
#pragma unroll
            for (int qt = 0; qt < 2; ++qt) {
                float p[4][4];
#pragma unroll
                for (int t = 0; t < 4; ++t)
#pragma unroll
                    for (int r = 0; r < 4; ++r) {
                        float v = s[qt][t][r] * sc2;
                        if (maskIter) {
                            const int kv = kvb + t * 16 + 4 * g + r;
                            const int q  = qrow + qt * 16 + cn;
                            if (kv > q) v = -3.0e38f;
                        }
                        p[t][r] = v;
                    }
                // row max: in-register over 16, then across lane groups
                float mx = p[0][0];
#pragma unroll
                for (int t = 0; t < 4; ++t)
#pragma unroll
                    for (int r = 0; r < 4; ++r) mx = fmaxf(mx, p[t][r]);
                mx = fmaxf(mx, __shfl_xor(mx, 16));
                mx = fmaxf(mx, __shfl_xor(mx, 32));

                // T13 defer-max (wave-uniform)
                const bool need = !__all(mx <= mrow[qt] + 8.0f);
                float scl = 1.0f;
                if (need) {
                    const float mn = fmaxf(mrow[qt], mx);
                    scl = exp2f(mrow[qt] - mn);
                    mrow[qt] = mn;
                }
                float rs = 0.f;
#pragma unroll
                for (int t = 0; t < 4; ++t)
#pragma unroll
                    for (int r = 0; r < 4; ++r) {
                        const float e = exp2f(p[t][r] - mrow[qt]);
                        p[t][r] = e; rs += e;
                    }
                rs += __shfl_xor(rs, 16);
                rs += __shfl_xor(rs, 32);
                lrow[qt] = lrow[qt] * scl + rs;
                if (need) {
#pragma unroll
                    for (int r = 0; r < 4; ++r) {
                        const float sr = __shfl(scl, (lane & 48) | (4 * g + r));
#pragma unroll
                        for (int dt = 0; dt < 4; ++dt) ao[qt][dt][r] *= sr;
                    }
                }
                // pack P to bf16 pairs: wq[t*2]   = {p[t][0], p[t][1]}
                //                       wq[t*2+1] = {p[t][2], p[t][3]}
#pragma unroll
                for (int t = 0; t < 4; ++t) {
                    wq[qt][t * 2 + 0] = (unsigned short)f2bf(p[t][0]) |
                                        ((unsigned int)(unsigned short)f2bf(p[t][1]) << 16);
                    wq[qt][t * 2 + 1] = (unsigned short)f2bf(p[t][2]) |
                                        ((unsigned int)(unsigned short)f2bf(p[t][3]) << 16);
                }
            }

            // V fragments (B-operand) from LDS: col=cn=d-local, k = kv = c*32+kg8+j
            bf16x8 vf[2][4];
#pragma unroll
            for (int c = 0; c < 2; ++c)
#pragma unroll
                for (int dt = 0; dt < 4; ++dt)
                    vf[c][dt] = *(const bf16x8*)&vt[cur][(dt * 16 + cn) * 72 + c * 32 + kg8];

            // P redistribution: dest (g) chunk c needs tile 2c+(g>>1),
            // words from src lanes 2(g&1)*16+cn and +16.
            const int srcA = 2 * (g & 1) * 16 + cn;
            const int hi = g >> 1;
#pragma unroll
            for (int qt = 0; qt < 2; ++qt)
#pragma unroll
                for (int c = 0; c < 2; ++c) {
                    const int i0 = (2 * c) * 2;
                    const int i1 = (2 * c + 1) * 2;
                    union { unsigned int u[4]; bf16x8 v; } pu;
                    unsigned int x0, x1;
                    x0 = __shfl(wq[qt][i0 + 0], srcA);
                    x1 = __shfl(wq[qt][i1 + 0], srcA);
                    pu.u[0] = hi ? x1 : x0;
                    x0 = __shfl(wq[qt][i0 + 1], srcA);
                    x1 = __shfl(wq[qt][i1 + 1], srcA);
                    pu.u[1] = hi ? x1 : x0;
                    x0 = __shfl(wq[qt][i0 + 0], srcA + 16);
                    x1 = __shfl(wq[qt][i1 + 0], srcA + 16);
                    pu.u[2] = hi ? x1 : x0;
                    x0 = __shfl(wq[qt][i0 + 1], srcA + 16);
                    x1 = __shfl(wq[qt][i1 + 1], srcA + 16);
                    pu.u[3] = hi ? x1 : x0;
#pragma unroll
                    for (int dt = 0; dt < 4; ++dt)
                        ao[qt][dt] = mfma16(pu.v, vf[c][dt], ao[qt][dt]);
                }
        }

        // write prefetched V tile into the other buffer
        if (pf) {
#pragma unroll
            for (int i = 0; i < 8; ++i) {
                unsigned int pk = (unsigned short)r0[i] | ((unsigned int)(unsigned short)r1[i] << 16);
                *(unsigned int*)&vt[cur ^ 1][(sd0 + i) * 72 + skv] = pk;
            }
        }
        __syncthreads();
    }

    // epilogue: O row q-local = 4g+r, col d-local = cn; pull 1/l to row indexing
#pragma unroll
    for (int qt = 0; qt < 2; ++qt) {
        const float linv = 1.0f / lrow[qt];
#pragma unroll
        for (int r = 0; r < 4; ++r) {
            const float lr = __shfl(linv, (lane & 48) | (4 * g + r));
            const int q = qrow + qt * 16 + 4 * g + r;
#pragma unroll
            for (int dt = 0; dt < 4; ++dt)
                attn_out[(size_t)(b * TSEQ + q) * CDIM + h * HDIM + dt * 16 + cn] =
                    f2bf(ao[qt][dt][r] * lr);
        }
    }
}

// ---------------------------------------------------------------------------
// launch
// ---------------------------------------------------------------------------
extern "C" void kernel_launch(void* const* d_in, const int* in_sizes, int n_in,
                              void* d_out, int out_size, void* d_ws, size_t ws_size,
                              hipStream_t stream) {
    const float* x      = (const float*)d_in[0];
    const float* w_attn = (const float*)d_in[1];
    const float* b_attn = (const float*)d_in[2];
    const float* w_proj = (const float*)d_in[3];
    const float* b_proj = (const float*)d_in[4];
    float* out = (float*)d_out;

    char* ws = (char*)d_ws;
    short* x_bf   = (short*)ws;                          // 16 MiB; reused as attn out
    short* wqkvT  = (short*)(ws + (16u << 20));          //  6 MiB [3072][1024]
    short* wprojT = (short*)(ws + (22u << 20));          //  2 MiB [1024][1024]
    short* qkv    = (short*)(ws + (24u << 20));          // 48 MiB [8192][3072]

    f32_to_bf16_kernel<<<(MROWS * CDIM / 4 + 255) / 256, 256, 0, stream>>>(x, x_bf, MROWS * CDIM / 4);
    transpose_f32_bf16_kernel<<<dim3(C3 / 32, CDIM / 32), dim3(32, 8), 0, stream>>>(w_attn, wqkvT, CDIM, C3);
    transpose_f32_bf16_kernel<<<dim3(CDIM / 32, CDIM / 32), dim3(32, 8), 0, stream>>>(w_proj, wprojT, CDIM, CDIM);

    gemm_bt_kernel<short><<<dim3(C3 / 128, MROWS / 128), 256, 0, stream>>>(
        x_bf, wqkvT, b_attn, qkv, MROWS, C3, CDIM);

    attn_kernel<<<dim3(TSEQ / 128, BATCH * NHEAD), 256, 0, stream>>>(qkv, x_bf);

    gemm_bt_kernel<float><<<dim3(CDIM / 128, MROWS / 128), 256, 0, stream>>>(
        x_bf, wprojT, b_proj, out, MROWS, CDIM, CDIM);
}

// Round 3
// 281.986 us; speedup vs baseline: 1.8784x; 1.3008x over previous
//
#include <hip/hip_runtime.h>
#include <hip/hip_bf16.h>

// ---------------------------------------------------------------------------
// Problem constants: B=4, T=2048, C=1024, H=16, hd=64
// ---------------------------------------------------------------------------
#define BATCH 4
#define TSEQ  2048
#define CDIM  1024
#define NHEAD 16
#define HDIM  64
#define C3    3072
#define MROWS (BATCH * TSEQ)   // 8192

typedef short bf16x8 __attribute__((ext_vector_type(8)));
typedef __bf16 bf16v8 __attribute__((ext_vector_type(8)));
typedef float f32x4 __attribute__((ext_vector_type(4)));

#define AS1 __attribute__((address_space(1)))
#define AS3 __attribute__((address_space(3)))

__device__ __forceinline__ short f2bf(float x) {
    unsigned int u = __builtin_bit_cast(unsigned int, x);
    u += 0x7fffu + ((u >> 16) & 1u);   // round-to-nearest-even
    return (short)(u >> 16);
}

__device__ __forceinline__ unsigned int cvtpk(float lo, float hi) {
    unsigned int r;
    asm("v_cvt_pk_bf16_f32 %0, %1, %2" : "=v"(r) : "v"(lo), "v"(hi));
    return r;
}

__device__ __forceinline__ f32x4 mfma16(bf16x8 a, bf16x8 b, f32x4 c) {
    return __builtin_amdgcn_mfma_f32_16x16x32_bf16(
        __builtin_bit_cast(bf16v8, a), __builtin_bit_cast(bf16v8, b), c, 0, 0, 0);
}

// ---------------------------------------------------------------------------
// fp32 -> bf16 straight convert (vectorized, n multiple of 4)
// ---------------------------------------------------------------------------
__global__ void f32_to_bf16_kernel(const float* __restrict__ in,
                                   short* __restrict__ out, int n4) {
    int i = blockIdx.x * blockDim.x + threadIdx.x;
    if (i >= n4) return;
    float4 v = ((const float4*)in)[i];
    short4 o;
    o.x = f2bf(v.x); o.y = f2bf(v.y); o.z = f2bf(v.z); o.w = f2bf(v.w);
    ((short4*)out)[i] = o;
}

// ---------------------------------------------------------------------------
// fp32 [K][N] -> bf16 [N][K] transpose-convert (32x32 LDS tiles)
// ---------------------------------------------------------------------------
__global__ void transpose_f32_bf16_kernel(const float* __restrict__ in,
                                          short* __restrict__ out,
                                          int K, int N) {
    __shared__ float tile[32][33];
    const int n0 = blockIdx.x * 32, k0 = blockIdx.y * 32;
    const int tx = threadIdx.x, ty = threadIdx.y;   // (32,8)
#pragma unroll
    for (int j = 0; j < 4; ++j)
        tile[ty + j * 8][tx] = in[(size_t)(k0 + ty + j * 8) * N + n0 + tx];
    __syncthreads();
#pragma unroll
    for (int j = 0; j < 4; ++j)
        out[(size_t)(n0 + ty + j * 8) * K + k0 + tx] = f2bf(tile[tx][ty + j * 8]);
}

// ---------------------------------------------------------------------------
// bf16 GEMM, m97 structure: out[M][N] = A[M][K] * Bt[N][K]^T + bias[N]
// ---------------------------------------------------------------------------
template <typename OutT>
__global__ __launch_bounds__(256) void gemm_bt_kernel(
    const short* __restrict__ A, const short* __restrict__ Bt,
    const float* __restrict__ bias, OutT* __restrict__ out,
    int M, int N, int K) {
    __shared__ short a_lds[128 * 32];
    __shared__ short b_lds[128 * 32];

    const int tid = threadIdx.x;
    const int lane = tid & 63;
    const int w = tid >> 6;
    const int wm = w >> 1, wn = w & 1;
    const int m0 = blockIdx.y * 128;
    const int n0 = blockIdx.x * 128;

    f32x4 acc[4][4] = {};

    const int srow = lane >> 2;
    const int scol = (lane & 3) * 8;
    const short* ga0 = A + (size_t)(m0 + w * 32 + srow) * K + scol;
    const short* ga1 = A + (size_t)(m0 + w * 32 + 16 + srow) * K + scol;
    const short* gb0 = Bt + (size_t)(n0 + w * 32 + srow) * K + scol;
    const short* gb1 = Bt + (size_t)(n0 + w * 32 + 16 + srow) * K + scol;
    short* la0 = &a_lds[(w * 2 + 0) * 512];
    short* la1 = &a_lds[(w * 2 + 1) * 512];
    short* lb0 = &b_lds[(w * 2 + 0) * 512];
    short* lb1 = &b_lds[(w * 2 + 1) * 512];

    const int fr = lane & 15;
    const int kg = (lane >> 4) * 8;

    for (int kt = 0; kt < K; kt += 32) {
        __syncthreads();
        __builtin_amdgcn_global_load_lds((const AS1 void*)(ga0 + kt), (AS3 void*)la0, 16, 0, 0);
        __builtin_amdgcn_global_load_lds((const AS1 void*)(ga1 + kt), (AS3 void*)la1, 16, 0, 0);
        __builtin_amdgcn_global_load_lds((const AS1 void*)(gb0 + kt), (AS3 void*)lb0, 16, 0, 0);
        __builtin_amdgcn_global_load_lds((const AS1 void*)(gb1 + kt), (AS3 void*)lb1, 16, 0, 0);
        __syncthreads();

        bf16x8 af[4], bfv[4];
#pragma unroll
        for (int f = 0; f < 4; ++f)
            af[f] = *(const bf16x8*)&a_lds[(wm * 64 + f * 16 + fr) * 32 + kg];
#pragma unroll
        for (int g = 0; g < 4; ++g)
            bfv[g] = *(const bf16x8*)&b_lds[(wn * 64 + g * 16 + fr) * 32 + kg];
#pragma unroll
        for (int f = 0; f < 4; ++f)
#pragma unroll
            for (int g = 0; g < 4; ++g)
                acc[f][g] = mfma16(af[f], bfv[g], acc[f][g]);
    }

    const int r0 = (lane >> 4) * 4;
    const int cn = lane & 15;
#pragma unroll
    for (int f = 0; f < 4; ++f) {
#pragma unroll
        for (int g = 0; g < 4; ++g) {
            const int col = n0 + wn * 64 + g * 16 + cn;
            const float bv = bias[col];
#pragma unroll
            for (int r = 0; r < 4; ++r) {
                const int row = m0 + wm * 64 + f * 16 + r0 + r;
                const float v = acc[f][g][r] + bv;
                if constexpr (sizeof(OutT) == 2)
                    out[(size_t)row * N + col] = (OutT)f2bf(v);
                else
                    out[(size_t)row * N + col] = (OutT)v;
            }
        }
    }
}

// ---------------------------------------------------------------------------
// Flash attention v3 — swapped QK^T; K staged in LDS (dbuf, XOR-swizzled,
// global_load_lds prefetch); V^T dbuf in LDS (reg-staged); in-register
// softmax (exp2 domain, defer-max, cvt_pk packing); XCD-swizzled 1D grid
// with heavy q-blocks first.
// 1024 blocks, 256 threads = 4 waves; wave owns 32 q rows; KVBLK=64.
// ---------------------------------------------------------------------------
__global__ __launch_bounds__(256) void attn_kernel(const short* __restrict__ qkv,
                                                   short* __restrict__ attn_out) {
    __shared__ short vt[2][64 * 72];     // [buf][d*72 + kv]
    __shared__ short klds[2][64 * 64];   // [buf][kv*64 + d], 16B-chunk XOR-swizzled

    const int tid = threadIdx.x;
    const int lane = tid & 63;
    const int w = tid >> 6;

    // XCD-aware swizzle (nwg=1024, 8 XCDs -> 128 blocks each) + heavy-first
    const int bid = blockIdx.x;
    const int swz = (bid & 7) * 128 + (bid >> 3);
    const int bh = swz >> 4;             // 0..63 : (b,h)
    const int qi = 15 - (swz & 15);      // heavy blocks first within XCD
    const int b = bh >> 4;
    const int h = bh & 15;
    const int q0 = qi * 128;
    const int qrow = q0 + w * 32;

    const size_t base = (size_t)b * TSEQ * C3 + (size_t)h * HDIM;
    const int cn = lane & 15;
    const int g = lane >> 4;
    const int kg8 = g * 8;

    // Q fragments (B-operand): col=cn=q-local, k-elems = d
    bf16x8 qf[2][2];
#pragma unroll
    for (int qt = 0; qt < 2; ++qt)
#pragma unroll
        for (int ks = 0; ks < 2; ++ks)
            qf[qt][ks] = *(const bf16x8*)(qkv + base +
                (size_t)(qrow + qt * 16 + cn) * C3 + ks * 32 + kg8);

    f32x4 ao[2][4] = {};
    float mrow[2] = {0.f, 0.f};          // running max in log2 domain (T13: start 0)
    float lrow[2] = {0.f, 0.f};

    const int niter = (q0 + 128) / 64;

    // K staging geometry (global_load_lds, both-sides swizzle, rule #21):
    // wave w call c covers tile rows c*32 + w*8 + (lane>>3), phys chunk lane&7,
    // whose content is global chunk (lane&7)^(lane>>3).
    const short* kgl = qkv + base + 1024;
    const size_t ksrc = (size_t)(w * 8 + (lane >> 3)) * C3 + ((lane & 7) ^ (lane >> 3)) * 8;
    // K read swizzle: logical chunk jc at row R lives at jc ^ (R&7)
    const int cnl = cn & 7;
    const int krow = cn * 64;
    const int kx0 = ((g ^ cnl) * 8);           // ks=0: chunk g
    const int kx1 = (((g ^ 4) ^ cnl) * 8);     // ks=1: chunk 4+g

    // V staging: thread covers kv rows (skv, skv+1) x d cols sd0..sd0+7
    const int skv = (tid & 31) * 2;
    const int sd0 = (tid >> 5) * 8;
    const short* vbase = qkv + base + 2048;

    {   // prologue: stage K0 + V0
        __builtin_amdgcn_global_load_lds((const AS1 void*)(kgl + ksrc),
                                         (AS3 void*)&klds[0][w * 512], 16, 0, 0);
        __builtin_amdgcn_global_load_lds((const AS1 void*)(kgl + ksrc + (size_t)32 * C3),
                                         (AS3 void*)&klds[0][2048 + w * 512], 16, 0, 0);
        bf16x8 r0 = *(const bf16x8*)(vbase + (size_t)skv * C3 + sd0);
        bf16x8 r1 = *(const bf16x8*)(vbase + (size_t)(skv + 1) * C3 + sd0);
#pragma unroll
        for (int i = 0; i < 8; ++i) {
            unsigned int pk = (unsigned short)r0[i] | ((unsigned int)(unsigned short)r1[i] << 16);
            *(unsigned int*)&vt[0][(sd0 + i) * 72 + skv] = pk;
        }
    }
    __syncthreads();

    for (int kb = 0; kb < niter; ++kb) {
        const int kvb = kb * 64;
        const int cur = kb & 1;
        const bool pf = (kb + 1 < niter);

        // prefetch next K tile straight into LDS (lands before next barrier)
        if (pf) {
            const short* kn = kgl + ksrc + (size_t)(kvb + 64) * C3;
            __builtin_amdgcn_global_load_lds((const AS1 void*)kn,
                (AS3 void*)&klds[cur ^ 1][w * 512], 16, 0, 0);
            __builtin_amdgcn_global_load_lds((const AS1 void*)(kn + (size_t)32 * C3),
                (AS3 void*)&klds[cur ^ 1][2048 + w * 512], 16, 0, 0);
        }
        // prefetch next V tile into registers (written to LDS post-compute)
        bf16x8 r0, r1;
        if (pf) {
            r0 = *(const bf16x8*)(vbase + (size_t)(kvb + 64 + skv) * C3 + sd0);
            r1 = *(const bf16x8*)(vbase + (size_t)(kvb + 64 + skv + 1) * C3 + sd0);
        }

        if (kvb <= qrow + 31) {          // wave-uniform activity guard
            // S^T[kv][q]: K fragments from swizzled LDS, per kv-tile t
            f32x4 s[2][4] = {};
#pragma unroll
            for (int t = 0; t < 4; ++t) {
                const int rb = cur * 4096 + t * 1024 + krow;
                bf16x8 k0 = *(const bf16x8*)&klds[0][rb + kx0];
                bf16x8 k1 = *(const bf16x8*)&klds[0][rb + kx1];
                s[0][t] = mfma16(k0, qf[0][0], s[0][t]);
                s[0][t] = mfma16(k1, qf[0][1], s[0][t]);
                s[1][t] = mfma16(k0, qf[1][0], s[1][t]);
                s[1][t] = mfma16(k1, qf[1][1], s[1][t]);
            }

            const bool maskIter = (kvb + 63 > qrow);
            const float sc2 = 0.125f * 1.44269504088896f;   // scale * log2(e)

            unsigned int wq[2][8];
#pragma unroll
            for (int qt = 0; qt < 2; ++qt) {
                const float negm = -mrow[qt];
                float p[4][4];
                float mx = -3.0e38f;
#pragma unroll
                for (int t = 0; t < 4; ++t)
#pragma unroll
                    for (int r = 0; r < 4; ++r) {
                        float v = fmaf(s[qt][t][r], sc2, negm);
                        if (maskIter) {
                            const int kv = kvb + t * 16 + 4 * g + r;
                            const int q  = qrow + qt * 16 + cn;
                            if (kv > q) v = -3.0e38f;
                        }
                        p[t][r] = v;
                        mx = fmaxf(mx, v);
                    }
                mx = fmaxf(mx, __shfl_xor(mx, 16));
                mx = fmaxf(mx, __shfl_xor(mx, 32));

                const bool need = !__all(mx <= 8.0f);     // T13 defer-max
                float shift = 0.f, scl = 1.0f;
                if (need) {
                    shift = fmaxf(mx, 0.f);
                    scl = exp2f(-shift);
                    mrow[qt] += shift;
                }
                float rs = 0.f;
#pragma unroll
                for (int t = 0; t < 4; ++t)
#pragma unroll
                    for (int r = 0; r < 4; ++r) {
                        const float e = exp2f(p[t][r] - shift);
                        p[t][r] = e; rs += e;
                    }
                rs += __shfl_xor(rs, 16);
                rs += __shfl_xor(rs, 32);
                lrow[qt] = lrow[qt] * scl + rs;
                if (need) {
#pragma unroll
                    for (int r = 0; r < 4; ++r) {
                        const float sr = __shfl(scl, (lane & 48) | (4 * g + r));
#pragma unroll
                        for (int dt = 0; dt < 4; ++dt) ao[qt][dt][r] *= sr;
                    }
                }
#pragma unroll
                for (int t = 0; t < 4; ++t) {
                    wq[qt][t * 2 + 0] = cvtpk(p[t][0], p[t][1]);
                    wq[qt][t * 2 + 1] = cvtpk(p[t][2], p[t][3]);
                }
            }

            // V fragments (B-operand) from LDS
            bf16x8 vf[2][4];
#pragma unroll
            for (int c = 0; c < 2; ++c)
#pragma unroll
                for (int dt = 0; dt < 4; ++dt)
                    vf[c][dt] = *(const bf16x8*)&vt[cur][(dt * 16 + cn) * 72 + c * 32 + kg8];

            // P redistribution to PV A-fragment layout via shuffles
            const int srcA = 2 * (g & 1) * 16 + cn;
            const int hi = g >> 1;
#pragma unroll
            for (int qt = 0; qt < 2; ++qt)
#pragma unroll
                for (int c = 0; c < 2; ++c) {
                    const int i0 = (2 * c) * 2;
                    const int i1 = (2 * c + 1) * 2;
                    union { unsigned int u[4]; bf16x8 v; } pu;
                    unsigned int x0, x1;
                    x0 = __shfl(wq[qt][i0 + 0], srcA);
                    x1 = __shfl(wq[qt][i1 + 0], srcA);
                    pu.u[0] = hi ? x1 : x0;
                    x0 = __shfl(wq[qt][i0 + 1], srcA);
                    x1 = __shfl(wq[qt][i1 + 1], srcA);
                    pu.u[1] = hi ? x1 : x0;
                    x0 = __shfl(wq[qt][i0 + 0], srcA + 16);
                    x1 = __shfl(wq[qt][i1 + 0], srcA + 16);
                    pu.u[2] = hi ? x1 : x0;
                    x0 = __shfl(wq[qt][i0 + 1], srcA + 16);
                    x1 = __shfl(wq[qt][i1 + 1], srcA + 16);
                    pu.u[3] = hi ? x1 : x0;
#pragma unroll
                    for (int dt = 0; dt < 4; ++dt)
                        ao[qt][dt] = mfma16(pu.v, vf[c][dt], ao[qt][dt]);
                }
        }

        // write prefetched V tile into the other buffer
        if (pf) {
#pragma unroll
            for (int i = 0; i < 8; ++i) {
                unsigned int pk = (unsigned short)r0[i] | ((unsigned int)(unsigned short)r1[i] << 16);
                *(unsigned int*)&vt[cur ^ 1][(sd0 + i) * 72 + skv] = pk;
            }
        }
        __syncthreads();
    }

    // epilogue
#pragma unroll
    for (int qt = 0; qt < 2; ++qt) {
        const float linv = 1.0f / lrow[qt];
#pragma unroll
        for (int r = 0; r < 4; ++r) {
            const float lr = __shfl(linv, (lane & 48) | (4 * g + r));
            const int q = qrow + qt * 16 + 4 * g + r;
#pragma unroll
            for (int dt = 0; dt < 4; ++dt)
                attn_out[(size_t)(b * TSEQ + q) * CDIM + h * HDIM + dt * 16 + cn] =
                    f2bf(ao[qt][dt][r] * lr);
        }
    }
}

// ---------------------------------------------------------------------------
// launch
// ---------------------------------------------------------------------------
extern "C" void kernel_launch(void* const* d_in, const int* in_sizes, int n_in,
                              void* d_out, int out_size, void* d_ws, size_t ws_size,
                              hipStream_t stream) {
    const float* x      = (const float*)d_in[0];
    const float* w_attn = (const float*)d_in[1];
    const float* b_attn = (const float*)d_in[2];
    const float* w_proj = (const float*)d_in[3];
    const float* b_proj = (const float*)d_in[4];
    float* out = (float*)d_out;

    char* ws = (char*)d_ws;
    short* x_bf   = (short*)ws;                          // 16 MiB; reused as attn out
    short* wqkvT  = (short*)(ws + (16u << 20));          //  6 MiB [3072][1024]
    short* wprojT = (short*)(ws + (22u << 20));          //  2 MiB [1024][1024]
    short* qkv    = (short*)(ws + (24u << 20));          // 48 MiB [8192][3072]

    f32_to_bf16_kernel<<<(MROWS * CDIM / 4 + 255) / 256, 256, 0, stream>>>(x, x_bf, MROWS * CDIM / 4);
    transpose_f32_bf16_kernel<<<dim3(C3 / 32, CDIM / 32), dim3(32, 8), 0, stream>>>(w_attn, wqkvT, CDIM, C3);
    transpose_f32_bf16_kernel<<<dim3(CDIM / 32, CDIM / 32), dim3(32, 8), 0, stream>>>(w_proj, wprojT, CDIM, CDIM);

    gemm_bt_kernel<short><<<dim3(C3 / 128, MROWS / 128), 256, 0, stream>>>(
        x_bf, wqkvT, b_attn, qkv, MROWS, C3, CDIM);

    attn_kernel<<<dim3(TSEQ / 128 * BATCH * NHEAD), 256, 0, stream>>>(qkv, x_bf);

    gemm_bt_kernel<float><<<dim3(CDIM / 128, MROWS / 128), 256, 0, stream>>>(
        x_bf, wprojT, b_proj, out, MROWS, CDIM, CDIM);
}

// Round 4
// 221.834 us; speedup vs baseline: 2.3878x; 1.2712x over previous
//
#include <hip/hip_runtime.h>
#include <hip/hip_bf16.h>

// ---------------------------------------------------------------------------
// Problem constants: B=4, T=2048, C=1024, H=16, hd=64
// ---------------------------------------------------------------------------
#define BATCH 4
#define TSEQ  2048
#define CDIM  1024
#define NHEAD 16
#define HDIM  64
#define C3    3072
#define MROWS (BATCH * TSEQ)   // 8192

typedef short bf16x8 __attribute__((ext_vector_type(8)));
typedef __bf16 bf16v8 __attribute__((ext_vector_type(8)));
typedef float f32x4 __attribute__((ext_vector_type(4)));

#define AS1 __attribute__((address_space(1)))
#define AS3 __attribute__((address_space(3)))

__device__ __forceinline__ short f2bf(float x) {
    unsigned int u = __builtin_bit_cast(unsigned int, x);
    u += 0x7fffu + ((u >> 16) & 1u);   // round-to-nearest-even
    return (short)(u >> 16);
}

__device__ __forceinline__ unsigned int cvtpk(float lo, float hi) {
    unsigned int r;
    asm("v_cvt_pk_bf16_f32 %0, %1, %2" : "=v"(r) : "v"(lo), "v"(hi));
    return r;
}

__device__ __forceinline__ f32x4 mfma16(bf16x8 a, bf16x8 b, f32x4 c) {
    return __builtin_amdgcn_mfma_f32_16x16x32_bf16(
        __builtin_bit_cast(bf16v8, a), __builtin_bit_cast(bf16v8, b), c, 0, 0, 0);
}

// ---------------------------------------------------------------------------
// fp32 -> bf16 straight convert (vectorized, n multiple of 4)
// ---------------------------------------------------------------------------
__global__ void f32_to_bf16_kernel(const float* __restrict__ in,
                                   short* __restrict__ out, int n4) {
    int i = blockIdx.x * blockDim.x + threadIdx.x;
    if (i >= n4) return;
    float4 v = ((const float4*)in)[i];
    short4 o;
    o.x = f2bf(v.x); o.y = f2bf(v.y); o.z = f2bf(v.z); o.w = f2bf(v.w);
    ((short4*)out)[i] = o;
}

// ---------------------------------------------------------------------------
// fp32 [K][N] -> bf16 [N][K] transpose-convert (32x32 LDS tiles)
// ---------------------------------------------------------------------------
__global__ void transpose_f32_bf16_kernel(const float* __restrict__ in,
                                          short* __restrict__ out,
                                          int K, int N) {
    __shared__ float tile[32][33];
    const int n0 = blockIdx.x * 32, k0 = blockIdx.y * 32;
    const int tx = threadIdx.x, ty = threadIdx.y;   // (32,8)
#pragma unroll
    for (int j = 0; j < 4; ++j)
        tile[ty + j * 8][tx] = in[(size_t)(k0 + ty + j * 8) * N + n0 + tx];
    __syncthreads();
#pragma unroll
    for (int j = 0; j < 4; ++j)
        out[(size_t)(n0 + ty + j * 8) * K + k0 + tx] = f2bf(tile[tx][ty + j * 8]);
}

// ---------------------------------------------------------------------------
// bf16 GEMM, m97 structure: out[M][N] = A[M][K] * Bt[N][K]^T + bias[N]
// ---------------------------------------------------------------------------
template <typename OutT>
__global__ __launch_bounds__(256) void gemm_bt_kernel(
    const short* __restrict__ A, const short* __restrict__ Bt,
    const float* __restrict__ bias, OutT* __restrict__ out,
    int M, int N, int K) {
    __shared__ short a_lds[128 * 32];
    __shared__ short b_lds[128 * 32];

    const int tid = threadIdx.x;
    const int lane = tid & 63;
    const int w = tid >> 6;
    const int wm = w >> 1, wn = w & 1;
    const int m0 = blockIdx.y * 128;
    const int n0 = blockIdx.x * 128;

    f32x4 acc[4][4] = {};

    const int srow = lane >> 2;
    const int scol = (lane & 3) * 8;
    const short* ga0 = A + (size_t)(m0 + w * 32 + srow) * K + scol;
    const short* ga1 = A + (size_t)(m0 + w * 32 + 16 + srow) * K + scol;
    const short* gb0 = Bt + (size_t)(n0 + w * 32 + srow) * K + scol;
    const short* gb1 = Bt + (size_t)(n0 + w * 32 + 16 + srow) * K + scol;
    short* la0 = &a_lds[(w * 2 + 0) * 512];
    short* la1 = &a_lds[(w * 2 + 1) * 512];
    short* lb0 = &b_lds[(w * 2 + 0) * 512];
    short* lb1 = &b_lds[(w * 2 + 1) * 512];

    const int fr = lane & 15;
    const int kg = (lane >> 4) * 8;

    for (int kt = 0; kt < K; kt += 32) {
        __syncthreads();
        __builtin_amdgcn_global_load_lds((const AS1 void*)(ga0 + kt), (AS3 void*)la0, 16, 0, 0);
        __builtin_amdgcn_global_load_lds((const AS1 void*)(ga1 + kt), (AS3 void*)la1, 16, 0, 0);
        __builtin_amdgcn_global_load_lds((const AS1 void*)(gb0 + kt), (AS3 void*)lb0, 16, 0, 0);
        __builtin_amdgcn_global_load_lds((const AS1 void*)(gb1 + kt), (AS3 void*)lb1, 16, 0, 0);
        __syncthreads();

        bf16x8 af[4], bfv[4];
#pragma unroll
        for (int f = 0; f < 4; ++f)
            af[f] = *(const bf16x8*)&a_lds[(wm * 64 + f * 16 + fr) * 32 + kg];
#pragma unroll
        for (int g = 0; g < 4; ++g)
            bfv[g] = *(const bf16x8*)&b_lds[(wn * 64 + g * 16 + fr) * 32 + kg];
#pragma unroll
        for (int f = 0; f < 4; ++f)
#pragma unroll
            for (int g = 0; g < 4; ++g)
                acc[f][g] = mfma16(af[f], bfv[g], acc[f][g]);
    }

    const int r0 = (lane >> 4) * 4;
    const int cn = lane & 15;
#pragma unroll
    for (int f = 0; f < 4; ++f) {
#pragma unroll
        for (int g = 0; g < 4; ++g) {
            const int col = n0 + wn * 64 + g * 16 + cn;
            const float bv = bias[col];
#pragma unroll
            for (int r = 0; r < 4; ++r) {
                const int row = m0 + wm * 64 + f * 16 + r0 + r;
                const float v = acc[f][g][r] + bv;
                if constexpr (sizeof(OutT) == 2)
                    out[(size_t)row * N + col] = (OutT)f2bf(v);
                else
                    out[(size_t)row * N + col] = (OutT)v;
            }
        }
    }
}

// ---------------------------------------------------------------------------
// Flash attention v4 — swapped QK^T; K LDS dbuf (XOR-swizzled, gll prefetch);
// V^T LDS dbuf; in-register softmax (exp2 domain, defer-max, cvt_pk);
// P redistribution via v_permlane{16,32}_swap (pure VALU, no LDS);
// CAUSAL PAIRING: each block runs two full passes (q-tile 15-p, then p) so
// all 512 blocks have identical duration -> flat occupancy, no tail.
// ---------------------------------------------------------------------------
__global__ __launch_bounds__(256) void attn_kernel(const short* __restrict__ qkv,
                                                   short* __restrict__ attn_out) {
    __shared__ short vt[2][64 * 72];     // [buf][d*72 + kv]
    __shared__ short klds[2][64 * 64];   // [buf][kv*64 + d], 16B-chunk XOR-swizzled

    const int tid = threadIdx.x;
    const int lane = tid & 63;
    const int w = tid >> 6;

    // XCD swizzle: 512 blocks, 64 per XCD; 8 bh per XCD (KV set ~4MB = L2)
    const int bid = blockIdx.x;
    const int swz = (bid & 7) * 64 + (bid >> 3);
    const int bh = swz >> 3;             // 0..63
    const int pairp = swz & 7;           // 0..7
    const int b = bh >> 4;
    const int h = bh & 15;

    const size_t base = (size_t)b * TSEQ * C3 + (size_t)h * HDIM;
    const int cn = lane & 15;
    const int g = lane >> 4;
    const int kg8 = g * 8;

    // K staging geometry (both-sides swizzle, rule #21)
    const short* kgl = qkv + base + 1024;
    const size_t ksrc = (size_t)(w * 8 + (lane >> 3)) * C3 + ((lane & 7) ^ (lane >> 3)) * 8;
    const int cnl = cn & 7;
    const int krow = cn * 64;
    const int kx0 = ((g ^ cnl) * 8);
    const int kx1 = (((g ^ 4) ^ cnl) * 8);

    // V staging geometry
    const int skv = (tid & 31) * 2;
    const int sd0 = (tid >> 5) * 8;
    const short* vbase = qkv + base + 2048;

    for (int pass = 0; pass < 2; ++pass) {
        const int qi = pass ? pairp : (15 - pairp);
        const int q0 = qi * 128;
        const int qrow = q0 + w * 32;
        const int niter = 2 * qi + 2;

        // Q fragments (B-operand): col=cn=q-local, k-elems = d
        bf16x8 qf[2][2];
#pragma unroll
        for (int qt = 0; qt < 2; ++qt)
#pragma unroll
            for (int ks = 0; ks < 2; ++ks)
                qf[qt][ks] = *(const bf16x8*)(qkv + base +
                    (size_t)(qrow + qt * 16 + cn) * C3 + ks * 32 + kg8);

        f32x4 ao[2][4] = {};
        float mrow[2] = {0.f, 0.f};
        float lrow[2] = {0.f, 0.f};

        {   // prologue: stage K0 + V0 (LDS free: previous pass ended w/ barrier)
            __builtin_amdgcn_global_load_lds((const AS1 void*)(kgl + ksrc),
                                             (AS3 void*)&klds[0][w * 512], 16, 0, 0);
            __builtin_amdgcn_global_load_lds((const AS1 void*)(kgl + ksrc + (size_t)32 * C3),
                                             (AS3 void*)&klds[0][2048 + w * 512], 16, 0, 0);
            bf16x8 r0 = *(const bf16x8*)(vbase + (size_t)skv * C3 + sd0);
            bf16x8 r1 = *(const bf16x8*)(vbase + (size_t)(skv + 1) * C3 + sd0);
#pragma unroll
            for (int i = 0; i < 8; ++i) {
                unsigned int pk = (unsigned short)r0[i] | ((unsigned int)(unsigned short)r1[i] << 16);
                *(unsigned int*)&vt[0][(sd0 + i) * 72 + skv] = pk;
            }
        }
        __syncthreads();

        for (int kb = 0; kb < niter; ++kb) {
            const int kvb = kb * 64;
            const int cur = kb & 1;
            const bool pf = (kb + 1 < niter);

            if (pf) {
                const short* kn = kgl + ksrc + (size_t)(kvb + 64) * C3;
                __builtin_amdgcn_global_load_lds((const AS1 void*)kn,
                    (AS3 void*)&klds[cur ^ 1][w * 512], 16, 0, 0);
                __builtin_amdgcn_global_load_lds((const AS1 void*)(kn + (size_t)32 * C3),
                    (AS3 void*)&klds[cur ^ 1][2048 + w * 512], 16, 0, 0);
            }
            bf16x8 r0, r1;
            if (pf) {
                r0 = *(const bf16x8*)(vbase + (size_t)(kvb + 64 + skv) * C3 + sd0);
                r1 = *(const bf16x8*)(vbase + (size_t)(kvb + 64 + skv + 1) * C3 + sd0);
            }

            if (kvb <= qrow + 31) {          // wave-uniform activity guard
                // S^T[kv][q]: K fragments from swizzled LDS
                f32x4 s[2][4] = {};
#pragma unroll
                for (int t = 0; t < 4; ++t) {
                    const int rb = cur * 4096 + t * 1024 + krow;
                    bf16x8 k0 = *(const bf16x8*)&klds[0][rb + kx0];
                    bf16x8 k1 = *(const bf16x8*)&klds[0][rb + kx1];
                    s[0][t] = mfma16(k0, qf[0][0], s[0][t]);
                    s[0][t] = mfma16(k1, qf[0][1], s[0][t]);
                    s[1][t] = mfma16(k0, qf[1][0], s[1][t]);
                    s[1][t] = mfma16(k1, qf[1][1], s[1][t]);
                }

                const bool maskIter = (kvb + 63 > qrow);
                const float sc2 = 0.125f * 1.44269504088896f;

                unsigned int wq[2][8];
#pragma unroll
                for (int qt = 0; qt < 2; ++qt) {
                    const float negm = -mrow[qt];
                    float p[4][4];
                    float mx = -3.0e38f;
#pragma unroll
                    for (int t = 0; t < 4; ++t)
#pragma unroll
                        for (int r = 0; r < 4; ++r) {
                            float v = fmaf(s[qt][t][r], sc2, negm);
                            if (maskIter) {
                                const int kv = kvb + t * 16 + 4 * g + r;
                                const int q  = qrow + qt * 16 + cn;
                                if (kv > q) v = -3.0e38f;
                            }
                            p[t][r] = v;
                            mx = fmaxf(mx, v);
                        }
                    mx = fmaxf(mx, __shfl_xor(mx, 16));
                    mx = fmaxf(mx, __shfl_xor(mx, 32));

                    const bool need = !__all(mx <= 8.0f);     // defer-max
                    float shift = 0.f, scl = 1.0f;
                    if (need) {
                        shift = fmaxf(mx, 0.f);
                        scl = exp2f(-shift);
                        mrow[qt] += shift;
                    }
                    float rs = 0.f;
#pragma unroll
                    for (int t = 0; t < 4; ++t)
#pragma unroll
                        for (int r = 0; r < 4; ++r) {
                            const float e = exp2f(p[t][r] - shift);
                            p[t][r] = e; rs += e;
                        }
                    rs += __shfl_xor(rs, 16);
                    rs += __shfl_xor(rs, 32);
                    lrow[qt] = lrow[qt] * scl + rs;
                    if (need) {
#pragma unroll
                        for (int r = 0; r < 4; ++r) {
                            const float sr = __shfl(scl, (lane & 48) | (4 * g + r));
#pragma unroll
                            for (int dt = 0; dt < 4; ++dt) ao[qt][dt][r] *= sr;
                        }
                    }
#pragma unroll
                    for (int t = 0; t < 4; ++t) {
                        wq[qt][t * 2 + 0] = cvtpk(p[t][0], p[t][1]);
                        wq[qt][t * 2 + 1] = cvtpk(p[t][2], p[t][3]);
                    }
                }

                // V fragments (B-operand) from LDS
                bf16x8 vf[2][4];
#pragma unroll
                for (int c = 0; c < 2; ++c)
#pragma unroll
                    for (int dt = 0; dt < 4; ++dt)
                        vf[c][dt] = *(const bf16x8*)&vt[cur][(dt * 16 + cn) * 72 + c * 32 + kg8];

                // P redistribution via permlane swaps (pure VALU):
                // dest group g needs words (4c+2*(g>>1), +1) from groups
                // (2(g&1), 2(g&1)+1).  swap32 then swap16 on (wq[4c],wq[4c+2])
                // yields u[0],u[2]; same on odd words yields u[1],u[3].
#pragma unroll
                for (int qt = 0; qt < 2; ++qt)
#pragma unroll
                    for (int c = 0; c < 2; ++c) {
                        union { unsigned int u[4]; bf16x8 v; } pu;
                        unsigned int a0 = wq[qt][4 * c + 0], b0 = wq[qt][4 * c + 2];
                        asm("v_permlane32_swap_b32 %0, %1" : "+v"(a0), "+v"(b0));
                        asm("v_permlane16_swap_b32 %0, %1" : "+v"(a0), "+v"(b0));
                        pu.u[0] = a0; pu.u[2] = b0;
                        unsigned int a1 = wq[qt][4 * c + 1], b1 = wq[qt][4 * c + 3];
                        asm("v_permlane32_swap_b32 %0, %1" : "+v"(a1), "+v"(b1));
                        asm("v_permlane16_swap_b32 %0, %1" : "+v"(a1), "+v"(b1));
                        pu.u[1] = a1; pu.u[3] = b1;
#pragma unroll
                        for (int dt = 0; dt < 4; ++dt)
                            ao[qt][dt] = mfma16(pu.v, vf[c][dt], ao[qt][dt]);
                    }
            }

            if (pf) {
#pragma unroll
                for (int i = 0; i < 8; ++i) {
                    unsigned int pk = (unsigned short)r0[i] | ((unsigned int)(unsigned short)r1[i] << 16);
                    *(unsigned int*)&vt[cur ^ 1][(sd0 + i) * 72 + skv] = pk;
                }
            }
            __syncthreads();
        }

        // epilogue for this pass
#pragma unroll
        for (int qt = 0; qt < 2; ++qt) {
            const float linv = 1.0f / lrow[qt];
#pragma unroll
            for (int r = 0; r < 4; ++r) {
                const float lr = __shfl(linv, (lane & 48) | (4 * g + r));
                const int q = qrow + qt * 16 + 4 * g + r;
#pragma unroll
                for (int dt = 0; dt < 4; ++dt)
                    attn_out[(size_t)(b * TSEQ + q) * CDIM + h * HDIM + dt * 16 + cn] =
                        f2bf(ao[qt][dt][r] * lr);
            }
        }
        __syncthreads();   // protect LDS before next pass restages
    }
}

// ---------------------------------------------------------------------------
// launch
// ---------------------------------------------------------------------------
extern "C" void kernel_launch(void* const* d_in, const int* in_sizes, int n_in,
                              void* d_out, int out_size, void* d_ws, size_t ws_size,
                              hipStream_t stream) {
    const float* x      = (const float*)d_in[0];
    const float* w_attn = (const float*)d_in[1];
    const float* b_attn = (const float*)d_in[2];
    const float* w_proj = (const float*)d_in[3];
    const float* b_proj = (const float*)d_in[4];
    float* out = (float*)d_out;

    char* ws = (char*)d_ws;
    short* x_bf   = (short*)ws;                          // 16 MiB; reused as attn out
    short* wqkvT  = (short*)(ws + (16u << 20));          //  6 MiB [3072][1024]
    short* wprojT = (short*)(ws + (22u << 20));          //  2 MiB [1024][1024]
    short* qkv    = (short*)(ws + (24u << 20));          // 48 MiB [8192][3072]

    f32_to_bf16_kernel<<<(MROWS * CDIM / 4 + 255) / 256, 256, 0, stream>>>(x, x_bf, MROWS * CDIM / 4);
    transpose_f32_bf16_kernel<<<dim3(C3 / 32, CDIM / 32), dim3(32, 8), 0, stream>>>(w_attn, wqkvT, CDIM, C3);
    transpose_f32_bf16_kernel<<<dim3(CDIM / 32, CDIM / 32), dim3(32, 8), 0, stream>>>(w_proj, wprojT, CDIM, CDIM);

    gemm_bt_kernel<short><<<dim3(C3 / 128, MROWS / 128), 256, 0, stream>>>(
        x_bf, wqkvT, b_attn, qkv, MROWS, C3, CDIM);

    attn_kernel<<<dim3(512), 256, 0, stream>>>(qkv, x_bf);

    gemm_bt_kernel<float><<<dim3(CDIM / 128, MROWS / 128), 256, 0, stream>>>(
        x_bf, wprojT, b_proj, out, MROWS, CDIM, CDIM);
}

// Round 5
// 212.330 us; speedup vs baseline: 2.4947x; 1.0448x over previous
//
#include <hip/hip_runtime.h>
#include <hip/hip_bf16.h>

// ---------------------------------------------------------------------------
// Problem constants: B=4, T=2048, C=1024, H=16, hd=64
// ---------------------------------------------------------------------------
#define BATCH 4
#define TSEQ  2048
#define CDIM  1024
#define NHEAD 16
#define HDIM  64
#define C3    3072
#define MROWS (BATCH * TSEQ)   // 8192

typedef short bf16x8 __attribute__((ext_vector_type(8)));
typedef __bf16 bf16v8 __attribute__((ext_vector_type(8)));
typedef float f32x4 __attribute__((ext_vector_type(4)));

#define AS1 __attribute__((address_space(1)))
#define AS3 __attribute__((address_space(3)))

__device__ __forceinline__ short f2bf(float x) {
    unsigned int u = __builtin_bit_cast(unsigned int, x);
    u += 0x7fffu + ((u >> 16) & 1u);   // round-to-nearest-even
    return (short)(u >> 16);
}

__device__ __forceinline__ unsigned int cvtpk(float lo, float hi) {
    unsigned int r;
    asm("v_cvt_pk_bf16_f32 %0, %1, %2" : "=v"(r) : "v"(lo), "v"(hi));
    return r;
}

__device__ __forceinline__ f32x4 mfma16(bf16x8 a, bf16x8 b, f32x4 c) {
    return __builtin_amdgcn_mfma_f32_16x16x32_bf16(
        __builtin_bit_cast(bf16v8, a), __builtin_bit_cast(bf16v8, b), c, 0, 0, 0);
}

// ---------------------------------------------------------------------------
// fp32 -> bf16 straight convert (vectorized, n multiple of 4)
// ---------------------------------------------------------------------------
__global__ void f32_to_bf16_kernel(const float* __restrict__ in,
                                   short* __restrict__ out, int n4) {
    int i = blockIdx.x * blockDim.x + threadIdx.x;
    if (i >= n4) return;
    float4 v = ((const float4*)in)[i];
    short4 o;
    o.x = f2bf(v.x); o.y = f2bf(v.y); o.z = f2bf(v.z); o.w = f2bf(v.w);
    ((short4*)out)[i] = o;
}

// ---------------------------------------------------------------------------
// fp32 [K][N] -> bf16 [N][K] transpose-convert (32x32 LDS tiles)
// ---------------------------------------------------------------------------
__global__ void transpose_f32_bf16_kernel(const float* __restrict__ in,
                                          short* __restrict__ out,
                                          int K, int N) {
    __shared__ float tile[32][33];
    const int n0 = blockIdx.x * 32, k0 = blockIdx.y * 32;
    const int tx = threadIdx.x, ty = threadIdx.y;   // (32,8)
#pragma unroll
    for (int j = 0; j < 4; ++j)
        tile[ty + j * 8][tx] = in[(size_t)(k0 + ty + j * 8) * N + n0 + tx];
    __syncthreads();
#pragma unroll
    for (int j = 0; j < 4; ++j)
        out[(size_t)(n0 + ty + j * 8) * K + k0 + tx] = f2bf(tile[tx][ty + j * 8]);
}

// ---------------------------------------------------------------------------
// bf16 GEMM, m97 structure: out[M][N] = A[M][K] * Bt[N][K]^T + bias[N]
// ---------------------------------------------------------------------------
template <typename OutT>
__global__ __launch_bounds__(256) void gemm_bt_kernel(
    const short* __restrict__ A, const short* __restrict__ Bt,
    const float* __restrict__ bias, OutT* __restrict__ out,
    int M, int N, int K) {
    __shared__ short a_lds[128 * 32];
    __shared__ short b_lds[128 * 32];

    const int tid = threadIdx.x;
    const int lane = tid & 63;
    const int w = tid >> 6;
    const int wm = w >> 1, wn = w & 1;
    const int m0 = blockIdx.y * 128;
    const int n0 = blockIdx.x * 128;

    f32x4 acc[4][4] = {};

    const int srow = lane >> 2;
    const int scol = (lane & 3) * 8;
    const short* ga0 = A + (size_t)(m0 + w * 32 + srow) * K + scol;
    const short* ga1 = A + (size_t)(m0 + w * 32 + 16 + srow) * K + scol;
    const short* gb0 = Bt + (size_t)(n0 + w * 32 + srow) * K + scol;
    const short* gb1 = Bt + (size_t)(n0 + w * 32 + 16 + srow) * K + scol;
    short* la0 = &a_lds[(w * 2 + 0) * 512];
    short* la1 = &a_lds[(w * 2 + 1) * 512];
    short* lb0 = &b_lds[(w * 2 + 0) * 512];
    short* lb1 = &b_lds[(w * 2 + 1) * 512];

    const int fr = lane & 15;
    const int kg = (lane >> 4) * 8;

    for (int kt = 0; kt < K; kt += 32) {
        __syncthreads();
        __builtin_amdgcn_global_load_lds((const AS1 void*)(ga0 + kt), (AS3 void*)la0, 16, 0, 0);
        __builtin_amdgcn_global_load_lds((const AS1 void*)(ga1 + kt), (AS3 void*)la1, 16, 0, 0);
        __builtin_amdgcn_global_load_lds((const AS1 void*)(gb0 + kt), (AS3 void*)lb0, 16, 0, 0);
        __builtin_amdgcn_global_load_lds((const AS1 void*)(gb1 + kt), (AS3 void*)lb1, 16, 0, 0);
        __syncthreads();

        bf16x8 af[4], bfv[4];
#pragma unroll
        for (int f = 0; f < 4; ++f)
            af[f] = *(const bf16x8*)&a_lds[(wm * 64 + f * 16 + fr) * 32 + kg];
#pragma unroll
        for (int g = 0; g < 4; ++g)
            bfv[g] = *(const bf16x8*)&b_lds[(wn * 64 + g * 16 + fr) * 32 + kg];
#pragma unroll
        for (int f = 0; f < 4; ++f)
#pragma unroll
            for (int g = 0; g < 4; ++g)
                acc[f][g] = mfma16(af[f], bfv[g], acc[f][g]);
    }

    const int r0 = (lane >> 4) * 4;
    const int cn = lane & 15;
#pragma unroll
    for (int f = 0; f < 4; ++f) {
#pragma unroll
        for (int g = 0; g < 4; ++g) {
            const int col = n0 + wn * 64 + g * 16 + cn;
            const float bv = bias[col];
#pragma unroll
            for (int r = 0; r < 4; ++r) {
                const int row = m0 + wm * 64 + f * 16 + r0 + r;
                const float v = acc[f][g][r] + bv;
                if constexpr (sizeof(OutT) == 2)
                    out[(size_t)row * N + col] = (OutT)f2bf(v);
                else
                    out[(size_t)row * N + col] = (OutT)v;
            }
        }
    }
}

// ---------------------------------------------------------------------------
// Flash attention v5 — q-tile 64 (16 rows/wave), fine-grained causal pairing:
// block = pair (31-p, p) of 64-row q-tiles -> 1024 uniform blocks, 4/CU,
// 16 waves/CU. Swapped QK^T; K LDS dbuf (XOR-swizzled, gll prefetch);
// V^T LDS dbuf; in-register softmax (exp2 domain, defer-max, cvt_pk,
// depth-4 reduction trees); P redistribution via v_permlane{16,32}_swap.
// ---------------------------------------------------------------------------
__global__ __launch_bounds__(256) void attn_kernel(const short* __restrict__ qkv,
                                                   short* __restrict__ attn_out) {
    __shared__ short vt[2][64 * 72];     // [buf][d*72 + kv]
    __shared__ short klds[2][64 * 64];   // [buf][kv*64 + d], 16B-chunk XOR-swizzled

    const int tid = threadIdx.x;
    const int lane = tid & 63;
    const int w = tid >> 6;

    // XCD swizzle: 1024 blocks, 128 per XCD; 8 bh per XCD (KV set ~4MB = L2)
    const int bid = blockIdx.x;
    const int swz = (bid & 7) * 128 + (bid >> 3);
    const int bh = swz >> 4;             // 0..63
    const int pairp = swz & 15;          // 0..15
    const int b = bh >> 4;
    const int h = bh & 15;

    const size_t base = (size_t)b * TSEQ * C3 + (size_t)h * HDIM;
    const int cn = lane & 15;
    const int g = lane >> 4;
    const int kg8 = g * 8;

    // K staging geometry (both-sides swizzle, rule #21)
    const short* kgl = qkv + base + 1024;
    const size_t ksrc = (size_t)(w * 8 + (lane >> 3)) * C3 + ((lane & 7) ^ (lane >> 3)) * 8;
    const int cnl = cn & 7;
    const int krow = cn * 64;
    const int kx0 = ((g ^ cnl) * 8);
    const int kx1 = (((g ^ 4) ^ cnl) * 8);

    // V staging geometry
    const int skv = (tid & 31) * 2;
    const int sd0 = (tid >> 5) * 8;
    const short* vbase = qkv + base + 2048;

    for (int pass = 0; pass < 2; ++pass) {
        const int qi = pass ? pairp : (31 - pairp);
        const int q0 = qi * 64;
        const int qrow = q0 + w * 16;
        const int niter = qi + 1;

        // Q fragments (B-operand): col=cn=q-local, k-elems = d
        bf16x8 qf[2];
#pragma unroll
        for (int ks = 0; ks < 2; ++ks)
            qf[ks] = *(const bf16x8*)(qkv + base +
                (size_t)(qrow + cn) * C3 + ks * 32 + kg8);

        f32x4 ao[4] = {};
        float mrow = 0.f;
        float lrow = 0.f;

        {   // prologue: stage K0 + V0
            __builtin_amdgcn_global_load_lds((const AS1 void*)(kgl + ksrc),
                                             (AS3 void*)&klds[0][w * 512], 16, 0, 0);
            __builtin_amdgcn_global_load_lds((const AS1 void*)(kgl + ksrc + (size_t)32 * C3),
                                             (AS3 void*)&klds[0][2048 + w * 512], 16, 0, 0);
            bf16x8 r0 = *(const bf16x8*)(vbase + (size_t)skv * C3 + sd0);
            bf16x8 r1 = *(const bf16x8*)(vbase + (size_t)(skv + 1) * C3 + sd0);
#pragma unroll
            for (int i = 0; i < 8; ++i) {
                unsigned int pk = (unsigned short)r0[i] | ((unsigned int)(unsigned short)r1[i] << 16);
                *(unsigned int*)&vt[0][(sd0 + i) * 72 + skv] = pk;
            }
        }
        __syncthreads();

        for (int kb = 0; kb < niter; ++kb) {
            const int kvb = kb * 64;
            const int cur = kb & 1;
            const bool pf = (kb + 1 < niter);

            if (pf) {
                const short* kn = kgl + ksrc + (size_t)(kvb + 64) * C3;
                __builtin_amdgcn_global_load_lds((const AS1 void*)kn,
                    (AS3 void*)&klds[cur ^ 1][w * 512], 16, 0, 0);
                __builtin_amdgcn_global_load_lds((const AS1 void*)(kn + (size_t)32 * C3),
                    (AS3 void*)&klds[cur ^ 1][2048 + w * 512], 16, 0, 0);
            }
            bf16x8 r0, r1;
            if (pf) {
                r0 = *(const bf16x8*)(vbase + (size_t)(kvb + 64 + skv) * C3 + sd0);
                r1 = *(const bf16x8*)(vbase + (size_t)(kvb + 64 + skv + 1) * C3 + sd0);
            }

            // S^T[kv][q]: K fragments from swizzled LDS
            f32x4 s[4] = {};
#pragma unroll
            for (int t = 0; t < 4; ++t) {
                const int rb = cur * 4096 + t * 1024 + krow;
                bf16x8 k0 = *(const bf16x8*)&klds[0][rb + kx0];
                bf16x8 k1 = *(const bf16x8*)&klds[0][rb + kx1];
                s[t] = mfma16(k0, qf[0], s[t]);
                s[t] = mfma16(k1, qf[1], s[t]);
            }

            const bool maskIter = (kb == niter - 1);   // diagonal block
            const float sc2 = 0.125f * 1.44269504088896f;

            const float negm = -mrow;
            float p[4][4];
#pragma unroll
            for (int t = 0; t < 4; ++t)
#pragma unroll
                for (int r = 0; r < 4; ++r) {
                    float v = fmaf(s[t][r], sc2, negm);
                    if (maskIter) {
                        const int kv = kvb + t * 16 + 4 * g + r;
                        const int q  = qrow + cn;
                        if (kv > q) v = -3.0e38f;
                    }
                    p[t][r] = v;
                }
            // depth-4 max tree
            float m0 = fmaxf(p[0][0], p[0][1]), m1 = fmaxf(p[0][2], p[0][3]);
            float m2 = fmaxf(p[1][0], p[1][1]), m3 = fmaxf(p[1][2], p[1][3]);
            float m4 = fmaxf(p[2][0], p[2][1]), m5 = fmaxf(p[2][2], p[2][3]);
            float m6 = fmaxf(p[3][0], p[3][1]), m7 = fmaxf(p[3][2], p[3][3]);
            m0 = fmaxf(m0, m1); m2 = fmaxf(m2, m3); m4 = fmaxf(m4, m5); m6 = fmaxf(m6, m7);
            m0 = fmaxf(m0, m2); m4 = fmaxf(m4, m6);
            float mx = fmaxf(m0, m4);
            mx = fmaxf(mx, __shfl_xor(mx, 16));
            mx = fmaxf(mx, __shfl_xor(mx, 32));

            const bool need = !__all(mx <= 8.0f);      // defer-max
            float shift = 0.f, scl = 1.0f;
            if (need) {
                shift = fmaxf(mx, 0.f);
                scl = exp2f(-shift);
                mrow += shift;
            }
#pragma unroll
            for (int t = 0; t < 4; ++t)
#pragma unroll
                for (int r = 0; r < 4; ++r)
                    p[t][r] = exp2f(p[t][r] - shift);
            // depth-4 sum tree
            float a0 = p[0][0] + p[0][1], a1 = p[0][2] + p[0][3];
            float a2 = p[1][0] + p[1][1], a3 = p[1][2] + p[1][3];
            float a4 = p[2][0] + p[2][1], a5 = p[2][2] + p[2][3];
            float a6 = p[3][0] + p[3][1], a7 = p[3][2] + p[3][3];
            a0 += a1; a2 += a3; a4 += a5; a6 += a7;
            a0 += a2; a4 += a6;
            float rs = a0 + a4;
            rs += __shfl_xor(rs, 16);
            rs += __shfl_xor(rs, 32);
            lrow = lrow * scl + rs;
            if (need) {
#pragma unroll
                for (int r = 0; r < 4; ++r) {
                    const float sr = __shfl(scl, (lane & 48) | (4 * g + r));
#pragma unroll
                    for (int dt = 0; dt < 4; ++dt) ao[dt][r] *= sr;
                }
            }
            unsigned int wq[8];
#pragma unroll
            for (int t = 0; t < 4; ++t) {
                wq[t * 2 + 0] = cvtpk(p[t][0], p[t][1]);
                wq[t * 2 + 1] = cvtpk(p[t][2], p[t][3]);
            }

            // V fragments (B-operand) from LDS
            bf16x8 vf[2][4];
#pragma unroll
            for (int c = 0; c < 2; ++c)
#pragma unroll
                for (int dt = 0; dt < 4; ++dt)
                    vf[c][dt] = *(const bf16x8*)&vt[cur][(dt * 16 + cn) * 72 + c * 32 + kg8];

            // P redistribution via permlane swaps (pure VALU)
#pragma unroll
            for (int c = 0; c < 2; ++c) {
                union { unsigned int u[4]; bf16x8 v; } pu;
                unsigned int p0 = wq[4 * c + 0], p2 = wq[4 * c + 2];
                asm("v_permlane32_swap_b32 %0, %1" : "+v"(p0), "+v"(p2));
                asm("v_permlane16_swap_b32 %0, %1" : "+v"(p0), "+v"(p2));
                pu.u[0] = p0; pu.u[2] = p2;
                unsigned int p1 = wq[4 * c + 1], p3 = wq[4 * c + 3];
                asm("v_permlane32_swap_b32 %0, %1" : "+v"(p1), "+v"(p3));
                asm("v_permlane16_swap_b32 %0, %1" : "+v"(p1), "+v"(p3));
                pu.u[1] = p1; pu.u[3] = p3;
#pragma unroll
                for (int dt = 0; dt < 4; ++dt)
                    ao[dt] = mfma16(pu.v, vf[c][dt], ao[dt]);
            }

            if (pf) {
#pragma unroll
                for (int i = 0; i < 8; ++i) {
                    unsigned int pk = (unsigned short)r0[i] | ((unsigned int)(unsigned short)r1[i] << 16);
                    *(unsigned int*)&vt[cur ^ 1][(sd0 + i) * 72 + skv] = pk;
                }
            }
            __syncthreads();
        }

        // epilogue for this pass: row q-local = 4g+r, col d-local = cn
        const float linv = 1.0f / lrow;
#pragma unroll
        for (int r = 0; r < 4; ++r) {
            const float lr = __shfl(linv, (lane & 48) | (4 * g + r));
            const int q = qrow + 4 * g + r;
#pragma unroll
            for (int dt = 0; dt < 4; ++dt)
                attn_out[(size_t)(b * TSEQ + q) * CDIM + h * HDIM + dt * 16 + cn] =
                    f2bf(ao[dt][r] * lr);
        }
        __syncthreads();   // protect LDS before next pass restages
    }
}

// ---------------------------------------------------------------------------
// launch
// ---------------------------------------------------------------------------
extern "C" void kernel_launch(void* const* d_in, const int* in_sizes, int n_in,
                              void* d_out, int out_size, void* d_ws, size_t ws_size,
                              hipStream_t stream) {
    const float* x      = (const float*)d_in[0];
    const float* w_attn = (const float*)d_in[1];
    const float* b_attn = (const float*)d_in[2];
    const float* w_proj = (const float*)d_in[3];
    const float* b_proj = (const float*)d_in[4];
    float* out = (float*)d_out;

    char* ws = (char*)d_ws;
    short* x_bf   = (short*)ws;                          // 16 MiB; reused as attn out
    short* wqkvT  = (short*)(ws + (16u << 20));          //  6 MiB [3072][1024]
    short* wprojT = (short*)(ws + (22u << 20));          //  2 MiB [1024][1024]
    short* qkv    = (short*)(ws + (24u << 20));          // 48 MiB [8192][3072]

    f32_to_bf16_kernel<<<(MROWS * CDIM / 4 + 255) / 256, 256, 0, stream>>>(x, x_bf, MROWS * CDIM / 4);
    transpose_f32_bf16_kernel<<<dim3(C3 / 32, CDIM / 32), dim3(32, 8), 0, stream>>>(w_attn, wqkvT, CDIM, C3);
    transpose_f32_bf16_kernel<<<dim3(CDIM / 32, CDIM / 32), dim3(32, 8), 0, stream>>>(w_proj, wprojT, CDIM, CDIM);

    gemm_bt_kernel<short><<<dim3(C3 / 128, MROWS / 128), 256, 0, stream>>>(
        x_bf, wqkvT, b_attn, qkv, MROWS, C3, CDIM);

    attn_kernel<<<dim3(1024), 256, 0, stream>>>(qkv, x_bf);

    gemm_bt_kernel<float><<<dim3(CDIM / 128, MROWS / 128), 256, 0, stream>>>(
        x_bf, wprojT, b_proj, out, MROWS, CDIM, CDIM);
}